// Round 10
// baseline (51.431 us; speedup 1.0000x reference)
//
#include <hip/hip_runtime.h>
#include <hip/hip_bf16.h>

#define HW 3136     // 56*56
#define CC 256
#define MM 72       // K*K*G (real)
#define HH 56
#define WW 56

typedef __attribute__((ext_vector_type(8))) short short8;   // 8 bf16 (4 VGPR)
typedef __attribute__((ext_vector_type(4))) float f32x4;    // MFMA acc / float4

#define WAITVM(n) asm volatile("s_waitcnt vmcnt(" #n ")" ::: "memory")
#define LGKM0     asm volatile("s_waitcnt lgkmcnt(0)" ::: "memory")
#define CFENCE    asm volatile("" ::: "memory")

__device__ __forceinline__ void blockbar() {
    CFENCE;
    __builtin_amdgcn_s_barrier();     // raw barrier: NO auto vmcnt(0) drain
    CFENCE;
}

__device__ inline unsigned short f2b(float f) {
    unsigned u; __builtin_memcpy(&u, &f, 4);
    unsigned r = u + 0x7fffu + ((u >> 16) & 1u);   // RNE to bf16
    return (unsigned short)(r >> 16);
}
__device__ inline float b2f(unsigned short s) {
    unsigned u = ((unsigned)s) << 16; float f; __builtin_memcpy(&f, &u, 4);
    return f;
}
__device__ __forceinline__ unsigned short f2b_native(float f) {
    __hip_bfloat16 h = __float2bfloat16(f);
    unsigned short s; __builtin_memcpy(&s, &h, 2);
    return s;
}

// fire-and-forget 16B global -> LDS DMA (counted in vmcnt; LDS dst is
// wave-uniform base + lane*16 for active lanes)
__device__ __forceinline__ void gl2lds16(const float* g, float* l) {
    __builtin_amdgcn_global_load_lds(
        (const __attribute__((address_space(1))) void*)g,
        (__attribute__((address_space(3))) void*)l, 16, 0, 0);
}

// ---------------------------------------------------------------------------
// k0: fold the two 1x1 convs into bf16 W [80][256] (rows 72..95 zero) and
// fp32 bias [80]. (verified, unchanged)
// ---------------------------------------------------------------------------
__global__ __launch_bounds__(256) void k0_combine(
    const float* __restrict__ w_reduce,   // [128][256]
    const float* __restrict__ b_reduce,   // [128]
    const float* __restrict__ w_span,     // [72][128]
    const float* __restrict__ b_span,     // [72]
    unsigned short* __restrict__ wbf,     // [80][256] bf16
    float* __restrict__ bcomb)            // [80]
{
    __shared__ float red[4][64];
    __shared__ float redb[256];

    const int m  = blockIdx.x;       // 0..79
    const int cq = blockIdx.y;       // 0..3
    const int t  = threadIdx.x;
    const int oq = t >> 6;           // o-chunk (wave id)
    const int cl = t & 63;
    const int c  = cq * 64 + cl;

    float acc = 0.f;
    if (m < MM) {
        const float* wsB = w_span   + m * 128 + oq * 32;
        const float* wrB = w_reduce + (size_t)(oq * 32) * 256 + c;
#pragma unroll 8
        for (int o = 0; o < 32; ++o)
            acc = fmaf(wsB[o], wrB[(size_t)o * 256], acc);
    }
    if (oq != 0) red[oq][cl] = acc;
    __syncthreads();
    if (oq == 0)
        wbf[m * 256 + c] = f2b(acc + red[1][cl] + red[2][cl] + red[3][cl]);

    if (cq == 0) {   // uniform per block -> safe to sync inside
        redb[t] = (m < MM && t < 128) ? w_span[m * 128 + t] * b_reduce[t] : 0.f;
        __syncthreads();
#pragma unroll
        for (int s2 = 128; s2 > 0; s2 >>= 1) {
            if (t < s2) redb[t] += redb[t + s2];
            __syncthreads();
        }
        if (t == 0) bcomb[m] = (m < MM ? b_span[m] : 0.f) + redb[0];
    }
}

// ---------------------------------------------------------------------------
// kA: pipelined MFMA GEMM (r7-VERIFIED kernel verbatim; only the ker store
// layout changed to the original [16][72][3136] so kB can read full rows).
// Ledger (stage = 3 VM ops t<320 / 2 else; prologue s0,s1):
//   p=0..6 : N = 3 / 2  (stage(p+1) in flight)
//   p==7   : N = 0      (one-time tail drain; epilogue stores follow)
// grid(448 = 8*56 XCD swizzle), block(448). LDS 58368 B -> 2 blk/CU.
// ---------------------------------------------------------------------------
__global__ __launch_bounds__(448, 4) void kA_gemm(
    const float* __restrict__ x,              // [16][256][3136] fp32
    const unsigned short* __restrict__ wbf,   // [80][256] bf16
    const float* __restrict__ bcomb,          // [80]
    unsigned short* __restrict__ kerb)        // [16][72][3136] bf16
{
    __shared__ __align__(16) float xsb[3 * 3584];           // 43008 B ring
    __shared__ __align__(16) unsigned short wsl[3][2560];   // 15360 B W ring

    const int L   = blockIdx.x;               // 0..447
    const int wk  = (L & 7) * 56 + (L >> 3);  // bijective (448 = 8*56)
    const int b   = wk / 28;
    const int rem = wk - b * 28;
    const int ht  = rem >> 1;                 // 0..13
    const int cs  = rem & 1;                  // column half
    const int h0  = ht * 4;
    const int c0  = cs * 28;

    const int t    = threadIdx.x;             // 0..447
    const int lane = t & 63;
    const int wv   = t >> 6;                  // wave 0..6 = GEMM n-tile
    const int l15  = lane & 15;
    const int q    = lane >> 4;

    const int chh   = t / 28;                 // 0..15 (staging decomposition)
    const int rem28 = t - chh * 28;
    const int rA    = rem28 / 7;
    const int qA    = rem28 - rA * 7;

    const float* xb = x + (size_t)b * CC * HW;

    // ---- per-thread constants (identical to verified r2/r4/r6/r7) ----
    const int nb   = wv * 16 + l15;                // GEMM n = tile px
    const int nb2  = q * 112 + nb;                 // B-frag base (j stride 448)
    const int swA  = (l15 ^ (l15 >> 2)) & 3;       // A-frag XOR swizzle
    const int aBo  = l15 * 32 + (q ^ swA) * 8;     // A-frag base (mt stride 512)
    const int cA   = ((chh & 3) << 3) | (chh >> 2);// x-DMA channel perm
    const int pxo  = (h0 + rA) * WW + c0 + qA * 4; // x-DMA pixel offset
    const int wswr = ((t >> 2) ^ (t >> 4)) & 3;    // wbf pre-swizzled source
    const unsigned short* wsrc0 = wbf + (t >> 2) * 256 + ((t & 3) ^ wswr) * 8;

    auto stageX = [&](int s) {                // 2 DMA (rows chh, chh+16)
        const float* sp = xb + (size_t)(s * 32 + cA) * HW + pxo;
        float* dp = xsb + (s % 3) * 3584 + t * 4;
        gl2lds16(sp, dp);
        gl2lds16(sp + (size_t)4 * HW, dp + 1792);
    };
    auto stageW = [&](int s) {                // 1 DMA, waves 0-4 only
        if (t < 320)
            gl2lds16((const float*)(wsrc0 + s * 32), (float*)(&wsl[s % 3][0]) + t * 4);
    };

    f32x4 acc[5];
#pragma unroll
    for (int mt = 0; mt < 5; ++mt)
#pragma unroll
        for (int r = 0; r < 4; ++r)
            acc[mt][r] = bcomb[mt * 16 + q * 4 + r];

    stageX(0); stageW(0);
    stageX(1); stageW(1);

#pragma unroll 1
    for (int p = 0; p < 8; ++p) {
        if (p < 7) { if (t < 320) WAITVM(3); else WAITVM(2); }
        else       { WAITVM(0); }
        blockbar();
        if (p < 6) { stageX(p + 2); stageW(p + 2); }

        const float* bufA = xsb + (p % 3) * 3584;
        const unsigned short* wp = &wsl[p % 3][0];
        union { short8 v; unsigned short u16[8]; } bq;
#pragma unroll
        for (int j = 0; j < 8; ++j)       // row j*4+q holds channel q*8+j
            bq.u16[j] = f2b_native(bufA[nb2 + j * 448]);
#pragma unroll
        for (int mt = 0; mt < 5; ++mt) {
            const short8 aq = *(const short8*)&wp[mt * 512 + aBo];
            acc[mt] = __builtin_amdgcn_mfma_f32_16x16x32_bf16(aq, bq.v, acc[mt], 0, 0, 0);
        }
    }

    // epilogue: store ker in [16][72][3136] (rows 72..79 dropped)
    const int pxg = (h0 + nb / 28) * WW + c0 + (nb % 28);
    unsigned short* kt = kerb + (size_t)b * MM * HW;
#pragma unroll
    for (int mt = 0; mt < 5; ++mt)
#pragma unroll
        for (int r = 0; r < 4; ++r) {
            const int m = mt * 16 + q * 4 + r;
            if (m < MM) kt[(size_t)m * HW + pxg] = f2b(acc[mt][r]);
        }
}

// ---------------------------------------------------------------------------
// kB: sliding-window apply. Block = (b, 8-ch chunk) owns the FULL 56-wide
// image, 7 phases of 8 output rows. Full-width rows -> zero col-halo
// staging; each x row staged EXACTLY ONCE (B fabric 99 -> 51.4 MB).
// x reg-staged (T14 load-early/write-late) into a 26-slot row ring
// (slot stride 484 words -> banks +4/row, conflict-free); ker DMA'd per
// 8-row batch into ring-3 klb (504 quads, partial-wave 2nd op).
// Thread = (ch 0..7, row_l 0..7, 8-col strip cq 0..6): 8 px, 2 f32x4 stores.
// Apply FP order verbatim from verified kernels (kh outer, kw inner).
//
// Pipeline (phase p): {xload(B(p+3)) [p<=3]; kd(p+2) [p<=4]; compute+store;
// xwrite(B(p+2)) [1<=p<=4, auto-wait regs]; WAITVM(N) drains kd(p+1);
// lgkm0; bar}. Prologue stages B0,B1,B2 + kd(0),kd(1), vmcnt(0), bar.
// N audited per wave (wave0 = t<64 has 2 kd ops): p<=3: 8/7; p==4: 6/5;
// p==5: 4; p==6: none. Stores ride ~2 phases; never vmcnt(0) in loop.
// Ring-26 collision audit: write rows [8p+16,8p+24) vs read [8p-1,8p+9):
// diff in [8,24], never 0 mod 26; diff-26 rows last read phase p-1 (bar'd).
// grid(512 = 8*64 XCD swizzle), block(448). LDS 74528 B -> 2 blk/CU.
// ---------------------------------------------------------------------------
__global__ __launch_bounds__(448, 4) void kB_apply(
    const float* __restrict__ x,              // [16][256][3136] fp32
    const unsigned short* __restrict__ kerb,  // [16][72][3136] bf16
    float* __restrict__ out)                  // [16][256][3136] fp32
{
    __shared__ __align__(16) float xs[26 * 484];            // 50336 B
    __shared__ __align__(16) unsigned short klb[3][4032];   // 24192 B

    const int L   = blockIdx.x;               // 0..511
    const int wk  = (L & 7) * 64 + (L >> 3);  // bijective (512 = 8*64)
    const int b   = wk >> 5;
    const int ck  = wk & 31;                  // 8-ch chunk
    const int chb = ck * 8;
    const int g   = ck >> 2;                  // group (32 ch)

    const int t   = threadIdx.x;              // 0..447
    const int ch  = t / 56;                   // 0..7
    const int rem = t - ch * 56;
    const int rl  = rem / 7;                  // row in 8-row band
    const int cq  = rem - rl * 7;             // 8-col strip 0..6
    const int cq8 = cq * 8;

    const float* xg = x + ((size_t)b * CC + chb) * HW;
    const unsigned short* kg = kerb + ((size_t)b * MM + g * 9) * HW;

    // ---- x stage maps: batch = 8 rows x 8 ch x 14 quads = 896 quads ----
    int sco[2], srw[2], sdw[2];
#pragma unroll
    for (int i = 0; i < 2; ++i) {
        const int f  = i * 448 + t;
        const int rw = f / 112;
        const int r2 = f - rw * 112;
        const int c2 = r2 / 14;
        const int q2 = r2 - c2 * 14;
        sco[i] = c2 * HW + q2 * 4;            // + row*WW (floats)
        srw[i] = rw;
        sdw[i] = c2 * 60 + q2 * 4;            // + slot*484 (floats)
    }
    // ---- ker stage maps (504 quads; 2nd op only lanes t<56 of wave 0) ----
    int koff0, koff1 = 0;
    {
        int f = t, k = f / 56, r3 = f - k * 56, rw = r3 / 7, c7 = r3 - rw * 7;
        koff0 = k * HW + rw * WW + 8 * c7;    // shorts; + 8s*WW per batch
        if (t < 56) {
            f = 448 + t; k = f / 56; r3 = f - k * 56; rw = r3 / 7; c7 = r3 - rw * 7;
            koff1 = k * HW + rw * WW + 8 * c7;
        }
    }

    const float lmf = (cq == 0) ? 0.f : 1.f;  // w-1 < 0
    const float rmf = (cq == 6) ? 0.f : 1.f;  // w+8 > 55 (col 56)

    f32x4 Ra[2], Rb[2], Rc[2];
    auto xload = [&](int s, f32x4* R) {       // rows [8s, 8s+8), no clamp needed
#pragma unroll
        for (int i = 0; i < 2; ++i)
            R[i] = *(const f32x4*)(xg + sco[i] + (8 * s + srw[i]) * WW);
    };
    auto xwrite = [&](int s, const f32x4* R) {
#pragma unroll
        for (int i = 0; i < 2; ++i) {
            const int slot = (8 * s + srw[i]) % 26;
            *(f32x4*)(xs + slot * 484 + sdw[i]) = R[i];
        }
    };
    auto kd = [&](int s) {                    // ker rows [8s, 8s+8) -> klb[s%3]
        float* dst = (float*)(&klb[s % 3][0]);
        gl2lds16((const float*)(kg + koff0 + (size_t)(8 * s) * WW), dst + t * 4);
        if (t < 56)
            gl2lds16((const float*)(kg + koff1 + (size_t)(8 * s) * WW),
                     dst + (448 + t) * 4);
    };

    // ---- prologue: B0,B1,B2 + kd(0),kd(1) ----
    xload(0, Ra); CFENCE; xload(1, Rb); CFENCE; xload(2, Rc); CFENCE;
    kd(0); CFENCE; kd(1); CFENCE;
    WAITVM(0);
    xwrite(0, Ra); xwrite(1, Rb); xwrite(2, Rc);
    LGKM0; blockbar();

    // ---- 7 phases ----
#pragma unroll 1
    for (int p = 0; p < 7; ++p) {
        // step 1: issue next loads / ker DMA
        if (p <= 3) { xload(p + 3, (p & 1) ? Rb : Ra); CFENCE; }
        if (p <= 4) { kd(p + 2); CFENCE; }

        // step 2: compute 8 px + store
        const int ro = 8 * p + rl;            // out row
        const unsigned short* kb = &klb[p % 3][0];
        float a[8] = {0.f, 0.f, 0.f, 0.f, 0.f, 0.f, 0.f, 0.f};
#pragma unroll
        for (int kh = 0; kh < 3; ++kh) {
            const int r  = ro - 1 + kh;
            const float vm = (r >= 0 && r < HH) ? 1.f : 0.f;
            const int rc = r < 0 ? 0 : (r > 55 ? 55 : r);
            const float* rowx = xs + (rc % 26) * 484 + ch * 60;
            const float lw  = rowx[cq8 > 0 ? cq8 - 1 : 0];
            const f32x4 q1  = *(const f32x4*)(rowx + cq8);
            const f32x4 q2  = *(const f32x4*)(rowx + cq8 + 4);
            const float rw2 = rowx[cq8 + 8 <= 55 ? cq8 + 8 : 55];
            float W[10] = {lw, q1.x, q1.y, q1.z, q1.w,
                           q2.x, q2.y, q2.z, q2.w, rw2};
            union { short8 v; unsigned short u[8]; } t0, t1, t2;
            const int tb = rl * 56 + cq8;
            t0.v = *(const short8*)&kb[(kh * 3 + 0) * 448 + tb];
            t1.v = *(const short8*)&kb[(kh * 3 + 1) * 448 + tb];
            t2.v = *(const short8*)&kb[(kh * 3 + 2) * 448 + tb];
            float k0[8], k1[8], k2[8];
#pragma unroll
            for (int j = 0; j < 8; ++j) {
                k0[j] = b2f(t0.u[j]) * vm;
                k1[j] = b2f(t1.u[j]) * vm;
                k2[j] = b2f(t2.u[j]) * vm;
            }
            k0[0] *= lmf;                     // tap reads col cq8-1
            k2[7] *= rmf;                     // tap reads col cq8+8
#pragma unroll
            for (int j = 0; j < 8; ++j) {
                a[j] = fmaf(k0[j], W[j],     a[j]);
                a[j] = fmaf(k1[j], W[j + 1], a[j]);
                a[j] = fmaf(k2[j], W[j + 2], a[j]);
            }
        }
        float* ob = out + ((size_t)b * CC + chb + ch) * HW + ro * WW + cq8;
        f32x4 o0 = {a[0], a[1], a[2], a[3]};
        f32x4 o1 = {a[4], a[5], a[6], a[7]};
        *(f32x4*)ob = o0;
        *(f32x4*)(ob + 4) = o1;
        CFENCE;

        // step 3: write staged rows (auto-wait on load regs)
        if (p >= 1 && p <= 4) xwrite(p + 2, (p & 1) ? Ra : Rb);

        // step 4: counted drain of kd(p+1); stores ride
        if (p <= 3)      { if (t < 64) WAITVM(8); else WAITVM(7); }
        else if (p == 4) { if (t < 64) WAITVM(6); else WAITVM(5); }
        else if (p == 5) { WAITVM(4); }
        if (p < 6) { LGKM0; blockbar(); }
    }
}

// ---------------------------------------------------------------------------
extern "C" void kernel_launch(void* const* d_in, const int* in_sizes, int n_in,
                              void* d_out, int out_size, void* d_ws, size_t ws_size,
                              hipStream_t stream) {
    const float* x        = (const float*)d_in[0];
    const float* w_reduce = (const float*)d_in[1];
    const float* b_reduce = (const float*)d_in[2];
    const float* w_span   = (const float*)d_in[3];
    const float* b_span   = (const float*)d_in[4];
    float* out = (float*)d_out;

    char* ws = (char*)d_ws;
    unsigned short* wbf   = (unsigned short*)ws;              // 40960 B
    float*          bcomb = (float*)(ws + 40960);             // 320 B
    unsigned short* kerb  = (unsigned short*)(ws + 41472);    // 7225344 B

    k0_combine<<<dim3(80, 4), 256, 0, stream>>>(w_reduce, b_reduce, w_span, b_span,
                                                wbf, bcomb);
    kA_gemm<<<dim3(448), 448, 0, stream>>>(x, wbf, bcomb, kerb);
    kB_apply<<<dim3(512), 448, 0, stream>>>(x, kerb, out);
}